// Round 6
// baseline (1377.027 us; speedup 1.0000x reference)
//
#include <hip/hip_runtime.h>

#define ALPHA 0.2f
#define NFEAT 256
#define NHID 64
#define NHEADS 3
#define NCLASS 40

typedef short short8 __attribute__((ext_vector_type(8)));
typedef float float4v __attribute__((ext_vector_type(4)));
typedef _Float16 half4_t __attribute__((ext_vector_type(4)));

#define INF __builtin_huge_valf()

__device__ __forceinline__ float lrelu_negexp(float x) {
    float l = fmaxf(x, 0.f) + ALPHA * fminf(x, 0.f);
    return __expf(-l);
}
__device__ __forceinline__ float elu1(float x) {
    return x > 0.f ? x : (__expf(x) - 1.f);
}
__device__ __forceinline__ unsigned short f2bf(float f) {
    unsigned int u = __float_as_uint(f);
    unsigned int r = (u + 0x7FFFu + ((u >> 16) & 1u)) >> 16;   // RN-even
    return (unsigned short)r;
}
__device__ __forceinline__ float bf2f(unsigned short h) {
    return __uint_as_float(((unsigned int)h) << 16);
}

// ---------------- convert x -> bf16 hi/lo split ----------------
__global__ __launch_bounds__(256) void cvt_x_k(const float* __restrict__ x,
        unsigned short* __restrict__ xhi, unsigned short* __restrict__ xlo, long n4) {
    long i = (long)blockIdx.x * 256 + threadIdx.x;
    if (i >= n4) return;
    float4 v = ((const float4*)x)[i];
    ushort4 hi, lo;
    hi.x = f2bf(v.x); lo.x = f2bf(v.x - bf2f(hi.x));
    hi.y = f2bf(v.y); lo.y = f2bf(v.y - bf2f(hi.y));
    hi.z = f2bf(v.z); lo.z = f2bf(v.z - bf2f(hi.z));
    hi.w = f2bf(v.w); lo.w = f2bf(v.w - bf2f(hi.w));
    ((ushort4*)xhi)[i] = hi;
    ((ushort4*)xlo)[i] = lo;
}

// ---------------- convert + transpose W: [3][256][64] -> Wt[192][256] hi/lo ----------------
__global__ __launch_bounds__(256) void cvt_w_k(const float* __restrict__ W,
        unsigned short* __restrict__ wthi, unsigned short* __restrict__ wtlo) {
    int i = blockIdx.x * 256 + threadIdx.x;   // over 3*64*256
    if (i >= NHEADS * NHID * NFEAT) return;
    int k = i & 255, nc = (i >> 8) & 63, head = i >> 14;
    float v = W[(size_t)head * NFEAT * NHID + (size_t)k * NHID + nc];
    unsigned short hi = f2bf(v);
    unsigned short lo = f2bf(v - bf2f(hi));
    wthi[i] = hi;   // layout: [(head*64+nc)][k], k contiguous
    wtlo[i] = lo;
}

// ---------------- GEMM1 via split-bf16 MFMA; epilogue writes fp16 h1h ----------------
__global__ __launch_bounds__(256) void gemm1_mfma_k(
        const unsigned short* __restrict__ xhi, const unsigned short* __restrict__ xlo,
        const unsigned short* __restrict__ wthi, const unsigned short* __restrict__ wtlo,
        _Float16* __restrict__ h1h, int N) {
    __shared__ unsigned short Ah[128 * 40];
    __shared__ unsigned short Al[128 * 40];
    __shared__ unsigned short Bh[192 * 40];
    __shared__ unsigned short Bl[192 * 40];
    const int tid = threadIdx.x;
    const int wave = tid >> 6, lane = tid & 63;
    const int quad = lane >> 4, l16 = lane & 15;
    const int row0 = blockIdx.x * 128;
    const int wm = (wave >> 1) * 64;
    const int wn = (wave & 1) * 96;

    float4v acc[4][6];
#pragma unroll
    for (int s = 0; s < 4; ++s)
#pragma unroll
        for (int t = 0; t < 6; ++t)
            acc[s][t] = (float4v){0.f, 0.f, 0.f, 0.f};

    for (int kc = 0; kc < NFEAT; kc += 32) {
#pragma unroll
        for (int rr = 0; rr < 2; ++rr) {
            int idx = rr * 256 + tid;
            int r = idx >> 2, kq = (idx & 3) * 8;
            int gr = row0 + r; if (gr >= N) gr = N - 1;
            size_t g = (size_t)gr * NFEAT + kc + kq;
            *(int4*)&Ah[r * 40 + kq] = *(const int4*)(xhi + g);
            *(int4*)&Al[r * 40 + kq] = *(const int4*)(xlo + g);
        }
#pragma unroll
        for (int rr = 0; rr < 3; ++rr) {
            int idx = rr * 256 + tid;
            int r = idx >> 2, kq = (idx & 3) * 8;
            size_t g = (size_t)r * NFEAT + kc + kq;
            *(int4*)&Bh[r * 40 + kq] = *(const int4*)(wthi + g);
            *(int4*)&Bl[r * 40 + kq] = *(const int4*)(wtlo + g);
        }
        __syncthreads();

        short8 ah[4], al[4];
#pragma unroll
        for (int s = 0; s < 4; ++s) {
            int m = wm + s * 16 + l16;
            ah[s] = *(const short8*)&Ah[m * 40 + quad * 8];
            al[s] = *(const short8*)&Al[m * 40 + quad * 8];
        }
#pragma unroll
        for (int t = 0; t < 6; ++t) {
            int n = wn + t * 16 + l16;
            short8 bh = *(const short8*)&Bh[n * 40 + quad * 8];
            short8 bl = *(const short8*)&Bl[n * 40 + quad * 8];
#pragma unroll
            for (int s = 0; s < 4; ++s) {
                acc[s][t] = __builtin_amdgcn_mfma_f32_16x16x32_bf16(ah[s], bh, acc[s][t], 0, 0, 0);
                acc[s][t] = __builtin_amdgcn_mfma_f32_16x16x32_bf16(ah[s], bl, acc[s][t], 0, 0, 0);
                acc[s][t] = __builtin_amdgcn_mfma_f32_16x16x32_bf16(al[s], bh, acc[s][t], 0, 0, 0);
            }
        }
        __syncthreads();
    }
#pragma unroll
    for (int s = 0; s < 4; ++s) {
#pragma unroll
        for (int r = 0; r < 4; ++r) {
            int grow = row0 + wm + s * 16 + quad * 4 + r;
            if (grow < N) {
#pragma unroll
                for (int t = 0; t < 6; ++t)
                    h1h[(size_t)grow * 192 + wn + t * 16 + l16] = (_Float16)acc[s][t][r];
            }
        }
    }
}

// ---------------- per-node logit dots, layer 1: writes padded ad4[N*4], as4[N] float4 ----------------
__global__ __launch_bounds__(256) void dots1_k(const _Float16* __restrict__ h1h,
        const float* __restrict__ a1, const float* __restrict__ a2,
        float* __restrict__ ad4, float* __restrict__ as4, int N) {
    int gt = blockIdx.x * 256 + threadIdx.x;
    int wid = gt >> 6, lane = gt & 63;
    if (wid >= N) return;
    const _Float16* hr = h1h + (size_t)wid * 192;
#pragma unroll
    for (int k = 0; k < 3; ++k) {
        float v = (float)hr[k*64 + lane];
        float da = v * a1[k*64 + lane];
        float db = v * a2[k*64 + lane];
#pragma unroll
        for (int o = 32; o > 0; o >>= 1) {
            da += __shfl_down(da, o, 64);
            db += __shfl_down(db, o, 64);
        }
        if (lane == 0) { ad4[wid*4+k] = da; as4[wid*4+k] = db; }
    }
}

// ---------------- CSR build: hist records per-edge rank ----------------
__global__ __launch_bounds__(256) void hist_k(const int* __restrict__ dst,
        int* __restrict__ cnt, int* __restrict__ rank, int E) {
    int e = blockIdx.x * 256 + threadIdx.x;
    if (e < E) rank[e] = atomicAdd(&cnt[dst[e]], 1);
}

__global__ __launch_bounds__(256) void scan1_k(const int* __restrict__ cnt,
        int* __restrict__ part, int* __restrict__ sums, int N) {
    __shared__ int s[256];
    int tid = threadIdx.x, b = blockIdx.x;
    int base = b * 2048 + tid * 8;
    int v[8]; int t = 0;
#pragma unroll
    for (int i = 0; i < 8; ++i) { int idx = base + i; v[i] = (idx < N) ? cnt[idx] : 0; t += v[i]; }
    s[tid] = t; __syncthreads();
    for (int o = 1; o < 256; o <<= 1) {
        int u = (tid >= o) ? s[tid - o] : 0;
        __syncthreads();
        s[tid] += u;
        __syncthreads();
    }
    int run = s[tid] - t;
#pragma unroll
    for (int i = 0; i < 8; ++i) { int idx = base + i; if (idx < N) part[idx] = run; run += v[i]; }
    if (tid == 255) sums[b] = s[255];
}

__global__ void scan2_k(int* sums, int nb) {
    if (threadIdx.x == 0 && blockIdx.x == 0) {
        int run = 0;
        for (int i = 0; i < nb; ++i) { int t = sums[i]; sums[i] = run; run += t; }
    }
}

__global__ __launch_bounds__(256) void scan3_k(const int* __restrict__ part,
        const int* __restrict__ sums, int* __restrict__ ptr, int N, int E) {
    int i = blockIdx.x * 256 + threadIdx.x;
    if (i < N) ptr[i] = part[i] + sums[i >> 11];
    if (i == 0) ptr[N] = E;
}

// ---------------- scatter: atomic-free, single 4B store ----------------
__global__ __launch_bounds__(256) void scatter_k(const int* __restrict__ dst,
        const int* __restrict__ src, const int* __restrict__ ptr,
        const int* __restrict__ rank, int* __restrict__ csr, int E) {
    int e = blockIdx.x * 256 + threadIdx.x;
    if (e < E) {
        int d = dst[e];
        csr[ptr[d] + rank[e]] = src[e];
    }
}

// ---------------- layer-1 aggregation: 3 heads in one pass, fused edge weights ----------------
__global__ __launch_bounds__(256) void agg1_k(const _Float16* __restrict__ h1h,
        const float4* __restrict__ as4, const float* __restrict__ ad4,
        const int* __restrict__ ptr, const int* __restrict__ csr,
        _Float16* __restrict__ out1h, int N) {
    int gt = blockIdx.x * 256 + threadIdx.x;
    int wid = gt >> 6, lane = gt & 63;
    if (wid >= N) return;
    int p0 = ptr[wid], p1 = ptr[wid + 1];
    float ad0 = ad4[wid*4+0], ad1v = ad4[wid*4+1], ad2v = ad4[wid*4+2];
    const _Float16* hbase = h1h + lane;
    float acc0 = 0, acc1 = 0, acc2 = 0, den0 = 0, den1 = 0, den2 = 0;
    int sSafe = csr[p0];

#define G 4
    int s[G]; float4 av[G];
    float va[G], vb[G], vc[G];
    // prefetch: out-of-range slots get as=+INF -> exp(-lrelu(INF)) = 0 weight
#define LD1(i, pos) { if ((pos) < p1) { s[i] = csr[(pos)]; av[i] = as4[s[i]]; } \
                      else { s[i] = sSafe; av[i] = make_float4(INF, INF, INF, 0.f); } }
#define LDR(i) { const _Float16* hp = hbase + (size_t)s[i] * 192; \
                 va[i] = (float)hp[0]; vb[i] = (float)hp[64]; vc[i] = (float)hp[128]; }
#pragma unroll
    for (int i = 0; i < G; ++i) LD1(i, p0 + i)
#pragma unroll
    for (int i = 0; i < G; ++i) LDR(i)

    for (int p = p0; p < p1; p += G) {
        float ca[G], cb[G], cc[G]; float4 cav[G];
#pragma unroll
        for (int i = 0; i < G; ++i) { ca[i] = va[i]; cb[i] = vb[i]; cc[i] = vc[i]; cav[i] = av[i]; }
        int np = p + G;
        if (np < p1) {
#pragma unroll
            for (int i = 0; i < G; ++i) LD1(i, np + i)
#pragma unroll
            for (int i = 0; i < G; ++i) LDR(i)
        }
#pragma unroll
        for (int i = 0; i < G; ++i) {
            float e0 = lrelu_negexp(ad0  + cav[i].x);
            float e1 = lrelu_negexp(ad1v + cav[i].y);
            float e2 = lrelu_negexp(ad2v + cav[i].z);
            acc0 = fmaf(e0, ca[i], acc0); den0 += e0;
            acc1 = fmaf(e1, cb[i], acc1); den1 += e1;
            acc2 = fmaf(e2, cc[i], acc2); den2 += e2;
        }
    }
#undef LD1
#undef LDR
#undef G
    size_t ob = (size_t)wid * 192;
    out1h[ob + lane]       = (_Float16)elu1(acc0 / (den0 + 1e-16f));
    out1h[ob + 64 + lane]  = (_Float16)elu1(acc1 / (den1 + 1e-16f));
    out1h[ob + 128 + lane] = (_Float16)elu1(acc2 / (den2 + 1e-16f));
}

// ---------------- GEMM2: h2h[N,40] = out1h[N,192] @ Wo[192,40], fp16 in/out ----------------
__global__ __launch_bounds__(256) void gemm2_k(const _Float16* __restrict__ X,
        const float* __restrict__ Wo, _Float16* __restrict__ h2h, int N) {
    __shared__ float Xs[32][193];
    __shared__ float Ws[192 * 40];
    const int tid = threadIdx.x;
    const int row0 = blockIdx.x * 32;
    for (int i = tid; i < 192 * 40; i += 256) Ws[i] = Wo[i];
    for (int i = tid; i < 32 * 48; i += 256) {
        int r = i / 48, c4 = (i % 48) * 4;
        int rr = row0 + r; if (rr >= N) rr = N - 1;
        half4_t v = *(const half4_t*)(X + (size_t)rr * 192 + c4);
        Xs[r][c4+0] = (float)v.x; Xs[r][c4+1] = (float)v.y;
        Xs[r][c4+2] = (float)v.z; Xs[r][c4+3] = (float)v.w;
    }
    __syncthreads();
    int rsub = tid >> 3;
    int f0 = (tid & 7) * 5;
    float acc[5] = {0, 0, 0, 0, 0};
    for (int c = 0; c < 192; ++c) {
        float xv = Xs[rsub][c];
#pragma unroll
        for (int j = 0; j < 5; ++j) acc[j] = fmaf(xv, Ws[c*40 + f0 + j], acc[j]);
    }
    int r = row0 + rsub;
    if (r < N) {
#pragma unroll
        for (int j = 0; j < 5; ++j) h2h[(size_t)r*40 + f0 + j] = (_Float16)acc[j];
    }
}

// ---------------- per-node logit dots, layer 2 (fp16 h2, stride 40) ----------------
__global__ __launch_bounds__(256) void dots2_k(const _Float16* __restrict__ h2h,
        const float* __restrict__ a1o, const float* __restrict__ a2o,
        float* __restrict__ ad2, float* __restrict__ as2, int N) {
    int gt = blockIdx.x * 256 + threadIdx.x;
    int wid = gt >> 6, lane = gt & 63;
    if (wid >= N) return;
    float v = 0.f, w1 = 0.f, w2 = 0.f;
    if (lane < 40) { v = (float)h2h[(size_t)wid*40 + lane]; w1 = a1o[lane]; w2 = a2o[lane]; }
    float da = v * w1, db = v * w2;
#pragma unroll
    for (int o = 32; o > 0; o >>= 1) { da += __shfl_down(da, o, 64); db += __shfl_down(db, o, 64); }
    if (lane == 0) { ad2[wid] = da; as2[wid] = db; }
}

// ---------------- layer-2 aggregation: fused edge weights, final ELU ----------------
__global__ __launch_bounds__(256) void agg2_k(const _Float16* __restrict__ h2h,
        const float* __restrict__ ad2, const float* __restrict__ as2,
        const int* __restrict__ ptr, const int* __restrict__ csr,
        float* __restrict__ out, int N) {
    int gt = blockIdx.x * 256 + threadIdx.x;
    int wid = gt >> 6, lane = gt & 63;
    if (wid >= N) return;
    int p0 = ptr[wid], p1 = ptr[wid + 1];
    float adv = ad2[wid];
    float acc = 0.f, den = 0.f;
    int sSafe = csr[p0];
    bool act = lane < 40;

#define G 8
    int s[G]; float a[G], v[G];
#define LD2(i, pos) { if ((pos) < p1) { s[i] = csr[(pos)]; a[i] = as2[s[i]]; } \
                      else { s[i] = sSafe; a[i] = INF; } }
#pragma unroll
    for (int i = 0; i < G; ++i) LD2(i, p0 + i)
#pragma unroll
    for (int i = 0; i < G; ++i) v[i] = act ? (float)h2h[(size_t)s[i] * 40 + lane] : 0.f;

    for (int p = p0; p < p1; p += G) {
        float cv[G], caw[G];
#pragma unroll
        for (int i = 0; i < G; ++i) { cv[i] = v[i]; caw[i] = a[i]; }
        int np = p + G;
        if (np < p1) {
#pragma unroll
            for (int i = 0; i < G; ++i) LD2(i, np + i)
#pragma unroll
            for (int i = 0; i < G; ++i) v[i] = act ? (float)h2h[(size_t)s[i] * 40 + lane] : 0.f;
        }
#pragma unroll
        for (int i = 0; i < G; ++i) {
            float e = lrelu_negexp(adv + caw[i]);
            acc = fmaf(e, cv[i], acc); den += e;
        }
    }
#undef LD2
#undef G
    float o = elu1(acc / (den + 1e-16f));
    if (act) out[(size_t)wid*40 + lane] = o;
}

extern "C" void kernel_launch(void* const* d_in, const int* in_sizes, int n_in,
                              void* d_out, int out_size, void* d_ws, size_t ws_size,
                              hipStream_t stream) {
    const float* x   = (const float*)d_in[0];
    const int*   ei  = (const int*)d_in[1];
    const float* W   = (const float*)d_in[2];
    const float* a1  = (const float*)d_in[3];
    const float* a2  = (const float*)d_in[4];
    const float* Wo  = (const float*)d_in[5];
    const float* a1o = (const float*)d_in[6];
    const float* a2o = (const float*)d_in[7];
    const int N = in_sizes[0] / NFEAT;
    const int E = in_sizes[1] / 2;
    const int* dst = ei;
    const int* src = ei + E;

    char* base = (char*)d_ws;
    size_t off = 0;
    auto alloc = [&](size_t bytes) { void* p = base + off; off += (bytes + 255) & ~(size_t)255; return p; };
    _Float16* h1h   = (_Float16*)alloc((size_t)N * 192 * 2);   // 38.4 MB
    _Float16* out1h = (_Float16*)alloc((size_t)N * 192 * 2);   // 38.4 MB
    int*      csr   = (int*)alloc((size_t)E * 4);              // 13.2 MB
    int*      rank  = (int*)alloc((size_t)E * 4);              // 13.2 MB
    char*     bufA  = (char*)alloc((size_t)N * NFEAT * 2);     // 51.2 MB: xhi, later h2h+ad2+as2
    char*     bufB  = (char*)alloc((size_t)N * NFEAT * 2);     // 51.2 MB: xlo only
    int*      ptr   = (int*)alloc((size_t)(N + 1) * 4);
    int*      cnt   = (int*)alloc((size_t)N * 4);
    int*      part  = (int*)alloc((size_t)N * 4);
    int*      sums  = (int*)alloc(1024);
    float*    ad4   = (float*)alloc((size_t)N * 4 * 4);        // padded [N][4]
    float*    as4   = (float*)alloc((size_t)N * 4 * 4);        // padded [N][4] (float4 loads)
    unsigned short* wthi = (unsigned short*)alloc((size_t)NHEADS * NHID * NFEAT * 2);
    unsigned short* wtlo = (unsigned short*)alloc((size_t)NHEADS * NHID * NFEAT * 2);

    unsigned short* xhi = (unsigned short*)bufA;              // dead after gemm1
    unsigned short* xlo = (unsigned short*)bufB;              // dead after gemm1
    _Float16* h2h = (_Float16*)bufA;                          // N*40*2 = 8 MB
    float*    ad2 = (float*)(bufA + (size_t)N * 40 * 2 + 1024);
    float*    as2 = ad2 + N;

    hipMemsetAsync(cnt, 0, (size_t)N * 4, stream);

    long n4 = (long)N * NFEAT / 4;
    cvt_x_k<<<(int)((n4 + 255) / 256), 256, 0, stream>>>(x, xhi, xlo, n4);
    cvt_w_k<<<(NHEADS * NHID * NFEAT + 255) / 256, 256, 0, stream>>>(W, wthi, wtlo);
    gemm1_mfma_k<<<(N + 127) / 128, 256, 0, stream>>>(xhi, xlo, wthi, wtlo, h1h, N);

    hist_k<<<(E + 255) / 256, 256, 0, stream>>>(dst, cnt, rank, E);
    int nb = (N + 2047) / 2048;
    scan1_k<<<nb, 256, 0, stream>>>(cnt, part, sums, N);
    scan2_k<<<1, 64, 0, stream>>>(sums, nb);
    scan3_k<<<(N + 255) / 256, 256, 0, stream>>>(part, sums, ptr, N, E);
    scatter_k<<<(E + 255) / 256, 256, 0, stream>>>(dst, src, ptr, rank, csr, E);

    dots1_k<<<(N + 3) / 4, 256, 0, stream>>>(h1h, a1, a2, ad4, as4, N);
    agg1_k<<<(N + 3) / 4, 256, 0, stream>>>(h1h, (const float4*)as4, ad4, ptr, csr, out1h, N);

    gemm2_k<<<(N + 31) / 32, 256, 0, stream>>>(out1h, Wo, h2h, N);
    dots2_k<<<(N + 3) / 4, 256, 0, stream>>>(h2h, a1o, a2o, ad2, as2, N);
    agg2_k<<<(N + 3) / 4, 256, 0, stream>>>(h2h, ad2, as2, ptr, csr, (float*)d_out, N);
}

// Round 7
// 1104.361 us; speedup vs baseline: 1.2469x; 1.2469x over previous
//
#include <hip/hip_runtime.h>

#define ALPHA 0.2f
#define NFEAT 256
#define NHID 64
#define NHEADS 3
#define NCLASS 40

typedef short short8 __attribute__((ext_vector_type(8)));
typedef float float4v __attribute__((ext_vector_type(4)));
typedef _Float16 half4_t __attribute__((ext_vector_type(4)));

__device__ __forceinline__ float lrelu_negexp(float x) {
    float l = fmaxf(x, 0.f) + ALPHA * fminf(x, 0.f);
    return __expf(-l);
}
__device__ __forceinline__ float elu1(float x) {
    return x > 0.f ? x : (__expf(x) - 1.f);
}
__device__ __forceinline__ unsigned short f2bf(float f) {
    unsigned int u = __float_as_uint(f);
    unsigned int r = (u + 0x7FFFu + ((u >> 16) & 1u)) >> 16;   // RN-even
    return (unsigned short)r;
}
__device__ __forceinline__ float bf2f(unsigned short h) {
    return __uint_as_float(((unsigned int)h) << 16);
}

// ---------------- convert x -> bf16 hi/lo split ----------------
__global__ __launch_bounds__(256) void cvt_x_k(const float* __restrict__ x,
        unsigned short* __restrict__ xhi, unsigned short* __restrict__ xlo, long n4) {
    long i = (long)blockIdx.x * 256 + threadIdx.x;
    if (i >= n4) return;
    float4 v = ((const float4*)x)[i];
    ushort4 hi, lo;
    hi.x = f2bf(v.x); lo.x = f2bf(v.x - bf2f(hi.x));
    hi.y = f2bf(v.y); lo.y = f2bf(v.y - bf2f(hi.y));
    hi.z = f2bf(v.z); lo.z = f2bf(v.z - bf2f(hi.z));
    hi.w = f2bf(v.w); lo.w = f2bf(v.w - bf2f(hi.w));
    ((ushort4*)xhi)[i] = hi;
    ((ushort4*)xlo)[i] = lo;
}

// ---------------- convert + transpose W: [3][256][64] -> Wt[192][256] hi/lo ----------------
__global__ __launch_bounds__(256) void cvt_w_k(const float* __restrict__ W,
        unsigned short* __restrict__ wthi, unsigned short* __restrict__ wtlo) {
    int i = blockIdx.x * 256 + threadIdx.x;   // over 3*64*256
    if (i >= NHEADS * NHID * NFEAT) return;
    int k = i & 255, nc = (i >> 8) & 63, head = i >> 14;
    float v = W[(size_t)head * NFEAT * NHID + (size_t)k * NHID + nc];
    unsigned short hi = f2bf(v);
    unsigned short lo = f2bf(v - bf2f(hi));
    wthi[i] = hi;   // layout: [(head*64+nc)][k], k contiguous
    wtlo[i] = lo;
}

// ---------------- GEMM1 via split-bf16 MFMA; epilogue writes fp16 h1h ----------------
__global__ __launch_bounds__(256) void gemm1_mfma_k(
        const unsigned short* __restrict__ xhi, const unsigned short* __restrict__ xlo,
        const unsigned short* __restrict__ wthi, const unsigned short* __restrict__ wtlo,
        _Float16* __restrict__ h1h, int N) {
    __shared__ unsigned short Ah[128 * 40];
    __shared__ unsigned short Al[128 * 40];
    __shared__ unsigned short Bh[192 * 40];
    __shared__ unsigned short Bl[192 * 40];
    const int tid = threadIdx.x;
    const int wave = tid >> 6, lane = tid & 63;
    const int quad = lane >> 4, l16 = lane & 15;
    const int row0 = blockIdx.x * 128;
    const int wm = (wave >> 1) * 64;
    const int wn = (wave & 1) * 96;

    float4v acc[4][6];
#pragma unroll
    for (int s = 0; s < 4; ++s)
#pragma unroll
        for (int t = 0; t < 6; ++t)
            acc[s][t] = (float4v){0.f, 0.f, 0.f, 0.f};

    for (int kc = 0; kc < NFEAT; kc += 32) {
#pragma unroll
        for (int rr = 0; rr < 2; ++rr) {
            int idx = rr * 256 + tid;
            int r = idx >> 2, kq = (idx & 3) * 8;
            int gr = row0 + r; if (gr >= N) gr = N - 1;
            size_t g = (size_t)gr * NFEAT + kc + kq;
            *(int4*)&Ah[r * 40 + kq] = *(const int4*)(xhi + g);
            *(int4*)&Al[r * 40 + kq] = *(const int4*)(xlo + g);
        }
#pragma unroll
        for (int rr = 0; rr < 3; ++rr) {
            int idx = rr * 256 + tid;
            int r = idx >> 2, kq = (idx & 3) * 8;
            size_t g = (size_t)r * NFEAT + kc + kq;
            *(int4*)&Bh[r * 40 + kq] = *(const int4*)(wthi + g);
            *(int4*)&Bl[r * 40 + kq] = *(const int4*)(wtlo + g);
        }
        __syncthreads();

        short8 ah[4], al[4];
#pragma unroll
        for (int s = 0; s < 4; ++s) {
            int m = wm + s * 16 + l16;
            ah[s] = *(const short8*)&Ah[m * 40 + quad * 8];
            al[s] = *(const short8*)&Al[m * 40 + quad * 8];
        }
#pragma unroll
        for (int t = 0; t < 6; ++t) {
            int n = wn + t * 16 + l16;
            short8 bh = *(const short8*)&Bh[n * 40 + quad * 8];
            short8 bl = *(const short8*)&Bl[n * 40 + quad * 8];
#pragma unroll
            for (int s = 0; s < 4; ++s) {
                acc[s][t] = __builtin_amdgcn_mfma_f32_16x16x32_bf16(ah[s], bh, acc[s][t], 0, 0, 0);
                acc[s][t] = __builtin_amdgcn_mfma_f32_16x16x32_bf16(ah[s], bl, acc[s][t], 0, 0, 0);
                acc[s][t] = __builtin_amdgcn_mfma_f32_16x16x32_bf16(al[s], bh, acc[s][t], 0, 0, 0);
            }
        }
        __syncthreads();
    }
#pragma unroll
    for (int s = 0; s < 4; ++s) {
#pragma unroll
        for (int r = 0; r < 4; ++r) {
            int grow = row0 + wm + s * 16 + quad * 4 + r;
            if (grow < N) {
#pragma unroll
                for (int t = 0; t < 6; ++t)
                    h1h[(size_t)grow * 192 + wn + t * 16 + l16] = (_Float16)acc[s][t][r];
            }
        }
    }
}

// ---------------- per-node logit dots, layer 1: writes padded ad4/as4 [N][4] ----------------
__global__ __launch_bounds__(256) void dots1_k(const _Float16* __restrict__ h1h,
        const float* __restrict__ a1, const float* __restrict__ a2,
        float* __restrict__ ad4, float* __restrict__ as4, int N) {
    int gt = blockIdx.x * 256 + threadIdx.x;
    int wid = gt >> 6, lane = gt & 63;
    if (wid >= N) return;
    const _Float16* hr = h1h + (size_t)wid * 192;
#pragma unroll
    for (int k = 0; k < 3; ++k) {
        float v = (float)hr[k*64 + lane];
        float da = v * a1[k*64 + lane];
        float db = v * a2[k*64 + lane];
#pragma unroll
        for (int o = 32; o > 0; o >>= 1) {
            da += __shfl_down(da, o, 64);
            db += __shfl_down(db, o, 64);
        }
        if (lane == 0) { ad4[wid*4+k] = da; as4[wid*4+k] = db; }
    }
}

// ---------------- CSR build: hist records per-edge rank ----------------
__global__ __launch_bounds__(256) void hist_k(const int* __restrict__ dst,
        int* __restrict__ cnt, int* __restrict__ rank, int E) {
    int e = blockIdx.x * 256 + threadIdx.x;
    if (e < E) rank[e] = atomicAdd(&cnt[dst[e]], 1);
}

__global__ __launch_bounds__(256) void scan1_k(const int* __restrict__ cnt,
        int* __restrict__ part, int* __restrict__ sums, int N) {
    __shared__ int s[256];
    int tid = threadIdx.x, b = blockIdx.x;
    int base = b * 2048 + tid * 8;
    int v[8]; int t = 0;
#pragma unroll
    for (int i = 0; i < 8; ++i) { int idx = base + i; v[i] = (idx < N) ? cnt[idx] : 0; t += v[i]; }
    s[tid] = t; __syncthreads();
    for (int o = 1; o < 256; o <<= 1) {
        int u = (tid >= o) ? s[tid - o] : 0;
        __syncthreads();
        s[tid] += u;
        __syncthreads();
    }
    int run = s[tid] - t;
#pragma unroll
    for (int i = 0; i < 8; ++i) { int idx = base + i; if (idx < N) part[idx] = run; run += v[i]; }
    if (tid == 255) sums[b] = s[255];
}

__global__ void scan2_k(int* sums, int nb) {
    if (threadIdx.x == 0 && blockIdx.x == 0) {
        int run = 0;
        for (int i = 0; i < nb; ++i) { int t = sums[i]; sums[i] = run; run += t; }
    }
}

__global__ __launch_bounds__(256) void scan3_k(const int* __restrict__ part,
        const int* __restrict__ sums, int* __restrict__ ptr, int N, int E) {
    int i = blockIdx.x * 256 + threadIdx.x;
    if (i < N) ptr[i] = part[i] + sums[i >> 11];
    if (i == 0) ptr[N] = E;
}

// ---------------- scatter: atomic-free, single 4B store (src only) ----------------
__global__ __launch_bounds__(256) void scatter_k(const int* __restrict__ dst,
        const int* __restrict__ src, const int* __restrict__ ptr,
        const int* __restrict__ rank, int* __restrict__ csr, int E) {
    int e = blockIdx.x * 256 + threadIdx.x;
    if (e < E) {
        int d = dst[e];
        csr[ptr[d] + rank[e]] = src[e];
    }
}

// ---------------- edge weights L1, row-parallel: wave per node, lanes over CSR row ----------------
__global__ __launch_bounds__(256) void edgew1_row_k(const int* __restrict__ ptr,
        const int* __restrict__ csr, const float4* __restrict__ ad4,
        const float4* __restrict__ as4, float4* __restrict__ w4, int N) {
    int gt = blockIdx.x * 256 + threadIdx.x;
    int wid = gt >> 6, lane = gt & 63;
    if (wid >= N) return;
    int p0 = ptr[wid], p1 = ptr[wid + 1];
    float4 ad = ad4[wid];
    for (int base = p0; base < p1; base += 64) {
        int e = base + lane;
        if (e < p1) {
            float4 as = as4[csr[e]];
            float4 w;
            w.x = lrelu_negexp(ad.x + as.x);
            w.y = lrelu_negexp(ad.y + as.y);
            w.z = lrelu_negexp(ad.z + as.z);
            w.w = 0.f;
            w4[e] = w;
        }
    }
}

// ---------------- layer-1 aggregation: 3 heads, one pass, PRECOMPUTED weights ----------------
__global__ __launch_bounds__(256) void agg1_k(const _Float16* __restrict__ h1h,
        const float4* __restrict__ w4,
        const int* __restrict__ ptr, const int* __restrict__ csr,
        _Float16* __restrict__ out1h, int N) {
    int gt = blockIdx.x * 256 + threadIdx.x;
    int wid = gt >> 6, lane = gt & 63;
    if (wid >= N) return;
    int p0 = ptr[wid], p1 = ptr[wid + 1];
    const _Float16* hbase = h1h + lane;
    float acc0 = 0, acc1 = 0, acc2 = 0, den0 = 0, den1 = 0, den2 = 0;
    int sSafe = csr[p0];

#define G 4
    int s[G]; float4 w[G];
    float va[G], vb[G], vc[G];
#define LD1(i, pos) { if ((pos) < p1) { s[i] = csr[(pos)]; w[i] = w4[(pos)]; } \
                      else { s[i] = sSafe; w[i] = make_float4(0.f,0.f,0.f,0.f); } }
#define LDR(i) { const _Float16* hp = hbase + (size_t)s[i] * 192; \
                 va[i] = (float)hp[0]; vb[i] = (float)hp[64]; vc[i] = (float)hp[128]; }
#pragma unroll
    for (int i = 0; i < G; ++i) LD1(i, p0 + i)
#pragma unroll
    for (int i = 0; i < G; ++i) LDR(i)

    for (int p = p0; p < p1; p += G) {
        float ca[G], cb[G], cc[G]; float4 cw[G];
#pragma unroll
        for (int i = 0; i < G; ++i) { ca[i] = va[i]; cb[i] = vb[i]; cc[i] = vc[i]; cw[i] = w[i]; }
        int np = p + G;
        if (np < p1) {
#pragma unroll
            for (int i = 0; i < G; ++i) LD1(i, np + i)
#pragma unroll
            for (int i = 0; i < G; ++i) LDR(i)
        }
#pragma unroll
        for (int i = 0; i < G; ++i) {
            acc0 = fmaf(cw[i].x, ca[i], acc0); den0 += cw[i].x;
            acc1 = fmaf(cw[i].y, cb[i], acc1); den1 += cw[i].y;
            acc2 = fmaf(cw[i].z, cc[i], acc2); den2 += cw[i].z;
        }
    }
#undef LD1
#undef LDR
#undef G
    size_t ob = (size_t)wid * 192;
    out1h[ob + lane]       = (_Float16)elu1(acc0 / (den0 + 1e-16f));
    out1h[ob + 64 + lane]  = (_Float16)elu1(acc1 / (den1 + 1e-16f));
    out1h[ob + 128 + lane] = (_Float16)elu1(acc2 / (den2 + 1e-16f));
}

// ---------------- GEMM2: h2h[N,64pad] = out1h[N,192] @ Wo[192,40], fp16 in/out ----------------
__global__ __launch_bounds__(256) void gemm2_k(const _Float16* __restrict__ X,
        const float* __restrict__ Wo, _Float16* __restrict__ h2h, int N) {
    __shared__ float Xs[32][193];
    __shared__ float Ws[192 * 40];
    const int tid = threadIdx.x;
    const int row0 = blockIdx.x * 32;
    for (int i = tid; i < 192 * 40; i += 256) Ws[i] = Wo[i];
    for (int i = tid; i < 32 * 48; i += 256) {
        int r = i / 48, c4 = (i % 48) * 4;
        int rr = row0 + r; if (rr >= N) rr = N - 1;
        half4_t v = *(const half4_t*)(X + (size_t)rr * 192 + c4);
        Xs[r][c4+0] = (float)v.x; Xs[r][c4+1] = (float)v.y;
        Xs[r][c4+2] = (float)v.z; Xs[r][c4+3] = (float)v.w;
    }
    __syncthreads();
    int rsub = tid >> 3;
    int f0 = (tid & 7) * 5;
    float acc[5] = {0, 0, 0, 0, 0};
    for (int c = 0; c < 192; ++c) {
        float xv = Xs[rsub][c];
#pragma unroll
        for (int j = 0; j < 5; ++j) acc[j] = fmaf(xv, Ws[c*40 + f0 + j], acc[j]);
    }
    int r = row0 + rsub;
    if (r < N) {
#pragma unroll
        for (int j = 0; j < 5; ++j) h2h[(size_t)r*64 + f0 + j] = (_Float16)acc[j];
    }
}

// ---------------- per-node logit dots, layer 2 (fp16 h2, stride 64) ----------------
__global__ __launch_bounds__(256) void dots2_k(const _Float16* __restrict__ h2h,
        const float* __restrict__ a1o, const float* __restrict__ a2o,
        float* __restrict__ ad2, float* __restrict__ as2, int N) {
    int gt = blockIdx.x * 256 + threadIdx.x;
    int wid = gt >> 6, lane = gt & 63;
    if (wid >= N) return;
    float v = 0.f, w1 = 0.f, w2 = 0.f;
    if (lane < 40) { v = (float)h2h[(size_t)wid*64 + lane]; w1 = a1o[lane]; w2 = a2o[lane]; }
    float da = v * w1, db = v * w2;
#pragma unroll
    for (int o = 32; o > 0; o >>= 1) { da += __shfl_down(da, o, 64); db += __shfl_down(db, o, 64); }
    if (lane == 0) { ad2[wid] = da; as2[wid] = db; }
}

// ---------------- edge weights L2, row-parallel ----------------
__global__ __launch_bounds__(256) void edgew2_row_k(const int* __restrict__ ptr,
        const int* __restrict__ csr, const float* __restrict__ ad2,
        const float* __restrict__ as2, float* __restrict__ w2, int N) {
    int gt = blockIdx.x * 256 + threadIdx.x;
    int wid = gt >> 6, lane = gt & 63;
    if (wid >= N) return;
    int p0 = ptr[wid], p1 = ptr[wid + 1];
    float ad = ad2[wid];
    for (int base = p0; base < p1; base += 64) {
        int e = base + lane;
        if (e < p1) w2[e] = lrelu_negexp(ad + as2[csr[e]]);
    }
}

// ---------------- layer-2 aggregation: precomputed weights, final ELU ----------------
__global__ __launch_bounds__(256) void agg2_k(const _Float16* __restrict__ h2h,
        const float* __restrict__ w2,
        const int* __restrict__ ptr, const int* __restrict__ csr,
        float* __restrict__ out, int N) {
    int gt = blockIdx.x * 256 + threadIdx.x;
    int wid = gt >> 6, lane = gt & 63;
    if (wid >= N) return;
    int p0 = ptr[wid], p1 = ptr[wid + 1];
    float acc = 0.f, den = 0.f;
    int sSafe = csr[p0];
    bool act = lane < 40;

#define G 8
    int s[G]; float w[G], v[G];
#define LD2(i, pos) { if ((pos) < p1) { s[i] = csr[(pos)]; w[i] = w2[(pos)]; } \
                      else { s[i] = sSafe; w[i] = 0.f; } }
#pragma unroll
    for (int i = 0; i < G; ++i) LD2(i, p0 + i)
#pragma unroll
    for (int i = 0; i < G; ++i) v[i] = act ? (float)h2h[(size_t)s[i] * 64 + lane] : 0.f;

    for (int p = p0; p < p1; p += G) {
        float cv[G], cw[G];
#pragma unroll
        for (int i = 0; i < G; ++i) { cv[i] = v[i]; cw[i] = w[i]; }
        int np = p + G;
        if (np < p1) {
#pragma unroll
            for (int i = 0; i < G; ++i) LD2(i, np + i)
#pragma unroll
            for (int i = 0; i < G; ++i) v[i] = act ? (float)h2h[(size_t)s[i] * 64 + lane] : 0.f;
        }
#pragma unroll
        for (int i = 0; i < G; ++i) { acc = fmaf(cw[i], cv[i], acc); den += cw[i]; }
    }
#undef LD2
#undef G
    float o = elu1(acc / (den + 1e-16f));
    if (act) out[(size_t)wid*40 + lane] = o;
}

extern "C" void kernel_launch(void* const* d_in, const int* in_sizes, int n_in,
                              void* d_out, int out_size, void* d_ws, size_t ws_size,
                              hipStream_t stream) {
    const float* x   = (const float*)d_in[0];
    const int*   ei  = (const int*)d_in[1];
    const float* W   = (const float*)d_in[2];
    const float* a1  = (const float*)d_in[3];
    const float* a2  = (const float*)d_in[4];
    const float* Wo  = (const float*)d_in[5];
    const float* a1o = (const float*)d_in[6];
    const float* a2o = (const float*)d_in[7];
    const int N = in_sizes[0] / NFEAT;
    const int E = in_sizes[1] / 2;
    const int* dst = ei;
    const int* src = ei + E;

    char* base = (char*)d_ws;
    size_t off = 0;
    auto alloc = [&](size_t bytes) { void* p = base + off; off += (bytes + 255) & ~(size_t)255; return p; };
    _Float16* h1h   = (_Float16*)alloc((size_t)N * 192 * 2);   // 38.4 MB
    _Float16* out1h = (_Float16*)alloc((size_t)N * 192 * 2);   // 38.4 MB
    int*      csr   = (int*)alloc((size_t)E * 4);              // 13.2 MB
    int*      rank  = (int*)alloc((size_t)E * 4);              // 13.2 MB
    float4*   w4    = (float4*)alloc((size_t)E * 16);          // 53 MB (w2 aliases later)
    char*     bufA  = (char*)alloc((size_t)N * NFEAT * 2);     // 51.2 MB: xhi, later h2h+ad2+as2
    char*     bufB  = (char*)alloc((size_t)N * NFEAT * 2);     // 51.2 MB: xlo only
    int*      ptr   = (int*)alloc((size_t)(N + 1) * 4);
    int*      cnt   = (int*)alloc((size_t)N * 4);
    int*      part  = (int*)alloc((size_t)N * 4);
    int*      sums  = (int*)alloc(1024);
    float*    ad4   = (float*)alloc((size_t)N * 4 * 4);        // padded [N][4]
    float*    as4   = (float*)alloc((size_t)N * 4 * 4);        // padded [N][4]
    unsigned short* wthi = (unsigned short*)alloc((size_t)NHEADS * NHID * NFEAT * 2);
    unsigned short* wtlo = (unsigned short*)alloc((size_t)NHEADS * NHID * NFEAT * 2);

    unsigned short* xhi = (unsigned short*)bufA;              // dead after gemm1
    unsigned short* xlo = (unsigned short*)bufB;              // dead after gemm1
    _Float16* h2h = (_Float16*)bufA;                          // N*64*2 = 12.8 MB
    float*    ad2 = (float*)(bufA + (size_t)N * 64 * 2 + 1024);
    float*    as2 = ad2 + N;
    float*    w2  = (float*)w4;                               // w4 dead after agg1

    hipMemsetAsync(cnt, 0, (size_t)N * 4, stream);

    long n4 = (long)N * NFEAT / 4;
    cvt_x_k<<<(int)((n4 + 255) / 256), 256, 0, stream>>>(x, xhi, xlo, n4);
    cvt_w_k<<<(NHEADS * NHID * NFEAT + 255) / 256, 256, 0, stream>>>(W, wthi, wtlo);
    gemm1_mfma_k<<<(N + 127) / 128, 256, 0, stream>>>(xhi, xlo, wthi, wtlo, h1h, N);

    hist_k<<<(E + 255) / 256, 256, 0, stream>>>(dst, cnt, rank, E);
    int nb = (N + 2047) / 2048;
    scan1_k<<<nb, 256, 0, stream>>>(cnt, part, sums, N);
    scan2_k<<<1, 64, 0, stream>>>(sums, nb);
    scan3_k<<<(N + 255) / 256, 256, 0, stream>>>(part, sums, ptr, N, E);
    scatter_k<<<(E + 255) / 256, 256, 0, stream>>>(dst, src, ptr, rank, csr, E);

    dots1_k<<<(N + 3) / 4, 256, 0, stream>>>(h1h, a1, a2, ad4, as4, N);
    edgew1_row_k<<<(N + 3) / 4, 256, 0, stream>>>(ptr, csr, (const float4*)ad4,
                                                  (const float4*)as4, w4, N);
    agg1_k<<<(N + 3) / 4, 256, 0, stream>>>(h1h, w4, ptr, csr, out1h, N);

    gemm2_k<<<(N + 31) / 32, 256, 0, stream>>>(out1h, Wo, h2h, N);
    dots2_k<<<(N + 3) / 4, 256, 0, stream>>>(h2h, a1o, a2o, ad2, as2, N);
    edgew2_row_k<<<(N + 3) / 4, 256, 0, stream>>>(ptr, csr, ad2, as2, w2, N);
    agg2_k<<<(N + 3) / 4, 256, 0, stream>>>(h2h, w2, ptr, csr, (float*)d_out, N);
}